// Round 9
// baseline (169.637 us; speedup 1.0000x reference)
//
#include <hip/hip_runtime.h>
#include <hip/hip_bf16.h>

typedef __bf16 bf16x8 __attribute__((ext_vector_type(8)));
typedef float f32x4 __attribute__((ext_vector_type(4)));

#define GN    1024
#define BATCH 64
#define CIN   256
#define COUT  256
#define NG    4                      // g's per persistent block
#define A_ELEMS (BATCH * CIN)        // 16384 ushorts = 32 KB
#define WSLICE  8192                 // per wave, per buffer: 64 o-rows x 32 k x 4B

#define G_AS __attribute__((address_space(1)))
#define L_AS __attribute__((address_space(3)))

static __device__ __forceinline__ void gload16(const void* g, void* l) {
  __builtin_amdgcn_global_load_lds((const G_AS void*)g, (L_AS void*)l, 16, 0, 0);
}

static __device__ __forceinline__ ushort f2bf(float f) {
  __hip_bfloat16 h = __float2bfloat16(f);
  return *reinterpret_cast<ushort*>(&h);
}
static __device__ __forceinline__ float bf2f(ushort u) {
  uint v = (uint)u << 16;
  return *reinterpret_cast<float*>(&v);
}

// ---------------------------------------------------------------------------
// Kernel 1: transpose + convert  x[b][i][g] (f32) -> xT[b][g][i^((b&7)<<3)] (bf16)
// xT stored PRE-SWIZZLED in i so k2 can DMA it linearly (rule 21).
// ---------------------------------------------------------------------------
__global__ __launch_bounds__(256) void k_transpose_convert(
    const float* __restrict__ x, ushort* __restrict__ xT)
{
  __shared__ float tile[64][65];
  const int g0 = blockIdx.x * 64;
  const int i0 = blockIdx.y * 64;
  const int b  = blockIdx.z;
  const int t  = threadIdx.x;
  const int a  = t & 15;
  const int r  = t >> 4;
  const int key = (b & 7) << 3;

  const float* xb = x + (size_t)b * CIN * GN;
#pragma unroll
  for (int p = 0; p < 4; ++p) {
    int ii = p * 16 + r;
    float4 v = *reinterpret_cast<const float4*>(
        &xb[(size_t)(i0 + ii) * GN + g0 + a * 4]);
    tile[ii][a * 4 + 0] = v.x;
    tile[ii][a * 4 + 1] = v.y;
    tile[ii][a * 4 + 2] = v.z;
    tile[ii][a * 4 + 3] = v.w;
  }
  __syncthreads();

  ushort* xTb = xT + (size_t)b * GN * CIN;
#pragma unroll
  for (int p = 0; p < 4; ++p) {
    int gg = p * 16 + r;
    ushort4 u;
    u.x = f2bf(tile[a * 4 + 0][gg]);
    u.y = f2bf(tile[a * 4 + 1][gg]);
    u.z = f2bf(tile[a * 4 + 2][gg]);
    u.w = f2bf(tile[a * 4 + 3][gg]);
    int isw = (i0 + a * 4) ^ key;
    *reinterpret_cast<ushort4*>(&xTb[(size_t)(g0 + gg) * CIN + isw]) = u;
  }
}

// ---------------------------------------------------------------------------
// Kernel 2: PERSISTENT per-group GEMM (round-6 structure, byte-identical).
// DIAGNOSTIC THIS ROUND: launched twice (idempotent) to measure t(k2).
// ---------------------------------------------------------------------------
__global__ __launch_bounds__(256) void k_group_gemm(
    const ushort* __restrict__ xT, const float* __restrict__ W,
    const float* __restrict__ bias, float* __restrict__ out,
    ushort* __restrict__ outT, int use_ws)
{
  __shared__ __align__(16) unsigned char lds[2 * A_ELEMS * 2 + 4 * 2 * WSLICE]; // 128 KB
  ushort* lA        = (ushort*)lds;
  unsigned char* lW = lds + 2 * A_ELEMS * 2;

  const int tid  = threadIdx.x;
  const int wave = tid >> 6;
  const int lane = tid & 63;
  const int g_base = blockIdx.x * NG;

  const int arow = lane & 15;
  const int colk = (lane >> 4) * 32;
  const int kq   = (lane >> 4) << 3;
  const int oc   = 64 * wave + arow;

  unsigned char* lWw = lW + wave * (2 * WSLICE);
  const int swz_src = ((lane & 7) ^ (lane >> 3)) << 4;
  const int wrow    = lane >> 3;

  auto stage_a = [&](int gg, int ab) {
    ushort* base = lA + ab * A_ELEMS;
#pragma unroll
    for (int j = 0; j < 8; ++j) {
      int b = 16 * wave + 2 * j + (lane >> 5);
      const ushort* gsrc = xT + ((size_t)b * GN + gg) * CIN + (lane & 31) * 8;
      gload16(gsrc, base + (16 * wave + 2 * j) * CIN);
    }
  };
  auto stage_w = [&](const float* wgp, int ks, int buf) {
    unsigned char* ldb = lWw + buf * WSLICE;
    const unsigned char* gb = (const unsigned char*)wgp + (size_t)ks * 128 + swz_src;
#pragma unroll
    for (int j = 0; j < 8; ++j) {
      gload16(gb + (size_t)(8 * j + wrow) * (CIN * 4), ldb + j * 1024);
    }
  };

  // ---- prologue: bias preload (16 loads), A(g0), W0, W1 ----
  float bvv[NG][4];
#pragma unroll
  for (int gi = 0; gi < NG; ++gi)
#pragma unroll
    for (int n = 0; n < 4; ++n)
      bvv[gi][n] = bias[(g_base + gi) * COUT + oc + n * 16];
  __builtin_amdgcn_sched_barrier(0);

  stage_a(g_base, 0);
  __builtin_amdgcn_sched_barrier(0);
  {
    const float* wg0 = W + ((size_t)g_base * COUT + 64 * wave) * CIN;
    stage_w(wg0, 0, 0);
    __builtin_amdgcn_sched_barrier(0);
    stage_w(wg0, 1, 1);
    __builtin_amdgcn_sched_barrier(0);
  }
  asm volatile("s_waitcnt vmcnt(8)" ::: "memory");
  __builtin_amdgcn_sched_barrier(0);
  __builtin_amdgcn_s_barrier();

#pragma unroll
  for (int gi = 0; gi < NG; ++gi) {
    const int g = g_base + gi;
    const ushort* lAc = lA + (gi & 1) * A_ELEMS;
    const float* wgp  = W + ((size_t)g * COUT + 64 * wave) * CIN;

    f32x4 acc[4][4];
#pragma unroll
    for (int m = 0; m < 4; ++m)
#pragma unroll
      for (int n = 0; n < 4; ++n)
        acc[m][n] = {0.f, 0.f, 0.f, 0.f};

#pragma unroll
    for (int ks = 0; ks < 8; ++ks) {
      if (gi < NG - 1) {
        if (ks == 6) { asm volatile("s_waitcnt vmcnt(16)" ::: "memory"); }
        else         { asm volatile("s_waitcnt vmcnt(8)"  ::: "memory"); }
      } else {
        if (ks == 7) { asm volatile("s_waitcnt vmcnt(0)"  ::: "memory"); }
        else         { asm volatile("s_waitcnt vmcnt(8)"  ::: "memory"); }
      }
      __builtin_amdgcn_sched_barrier(0);

      unsigned char* wb = lWw + (ks & 1) * WSLICE;
      const int key = (arow & 7) << 4;

      float4 f[4][2];
#pragma unroll
      for (int n = 0; n < 4; ++n) {
        int r = n * 16 + arow;
        f[n][0] = *reinterpret_cast<const float4*>(wb + r * 128 + (colk ^ key));
        f[n][1] = *reinterpret_cast<const float4*>(wb + r * 128 + ((colk + 16) ^ key));
      }
      bf16x8 afr[4];
      const int i0 = ks * 32 + kq;
#pragma unroll
      for (int m = 0; m < 4; ++m) {
        int row = m * 16 + arow;
        afr[m] = *reinterpret_cast<const bf16x8*>(
            &lAc[row * CIN + (i0 ^ ((row & 7) << 3))]);
      }

      asm volatile("s_waitcnt lgkmcnt(0)" ::: "memory");
      __builtin_amdgcn_sched_barrier(0);
      if (ks < 6) stage_w(wgp, ks + 2, ks & 1);
      if (ks == 4 && gi < NG - 1) stage_a(g + 1, (gi & 1) ^ 1);
      __builtin_amdgcn_sched_barrier(0);

      bf16x8 bfr[4];
#pragma unroll
      for (int n = 0; n < 4; ++n) {
        bfr[n][0] = (__bf16)f[n][0].x; bfr[n][1] = (__bf16)f[n][0].y;
        bfr[n][2] = (__bf16)f[n][0].z; bfr[n][3] = (__bf16)f[n][0].w;
        bfr[n][4] = (__bf16)f[n][1].x; bfr[n][5] = (__bf16)f[n][1].y;
        bfr[n][6] = (__bf16)f[n][1].z; bfr[n][7] = (__bf16)f[n][1].w;
      }

      __builtin_amdgcn_s_setprio(1);
#pragma unroll
      for (int m = 0; m < 4; ++m)
#pragma unroll
        for (int n = 0; n < 4; ++n)
          acc[m][n] = __builtin_amdgcn_mfma_f32_16x16x32_bf16(
              afr[m], bfr[n], acc[m][n], 0, 0, 0);
      __builtin_amdgcn_s_setprio(0);
    }

    // ---- epilogue for g ----
    if (use_ws) {
#pragma unroll
      for (int m = 0; m < 4; ++m) {
#pragma unroll
        for (int n = 0; n < 4; ++n) {
          int o = oc + n * 16;
#pragma unroll
          for (int j = 0; j < 4; ++j) {
            int b = m * 16 + ((lane >> 4) << 2) + j;
            __hip_bfloat16 h = __float2bfloat16(acc[m][n][j] + bvv[gi][n]);
            outT[((size_t)b * GN + g) * COUT + o] = *reinterpret_cast<ushort*>(&h);
          }
        }
      }
    } else {
#pragma unroll
      for (int m = 0; m < 4; ++m) {
#pragma unroll
        for (int n = 0; n < 4; ++n) {
          int o = oc + n * 16;
#pragma unroll
          for (int j = 0; j < 4; ++j) {
            int b = m * 16 + ((lane >> 4) << 2) + j;
            out[((size_t)b * COUT + o) * GN + g] = acc[m][n][j] + bvv[gi][n];
          }
        }
      }
    }
    __builtin_amdgcn_sched_barrier(0);

    if (gi < NG - 1) {
      const float* wgn = W + ((size_t)(g + 1) * COUT + 64 * wave) * CIN;
      stage_w(wgn, 0, 0);
      __builtin_amdgcn_sched_barrier(0);
      stage_w(wgn, 1, 1);
      __builtin_amdgcn_sched_barrier(0);
      asm volatile("s_waitcnt vmcnt(8)" ::: "memory");
      __builtin_amdgcn_sched_barrier(0);
      __builtin_amdgcn_s_barrier();
    }
  }
}

// ---------------------------------------------------------------------------
// Kernel 3: transpose  outT[b][g][o] (bf16) -> out[b][o][g] (f32)
// ---------------------------------------------------------------------------
__global__ __launch_bounds__(256) void k_transpose_out(
    const ushort* __restrict__ outT, float* __restrict__ out)
{
  __shared__ float tile[64][65];  // [g][o]
  const int g0 = blockIdx.x * 64;
  const int o0 = blockIdx.y * 64;
  const int b  = blockIdx.z;
  const int t  = threadIdx.x;
  const int a  = t & 15;
  const int r  = t >> 4;

  const ushort* src = outT + (size_t)b * GN * COUT;
#pragma unroll
  for (int p = 0; p < 4; ++p) {
    int gl = p * 16 + r;
    ushort4 u = *reinterpret_cast<const ushort4*>(
        &src[(size_t)(g0 + gl) * COUT + o0 + a * 4]);
    tile[gl][a * 4 + 0] = bf2f(u.x);
    tile[gl][a * 4 + 1] = bf2f(u.y);
    tile[gl][a * 4 + 2] = bf2f(u.z);
    tile[gl][a * 4 + 3] = bf2f(u.w);
  }
  __syncthreads();

  float* dst = out + (size_t)b * COUT * GN;
#pragma unroll
  for (int p = 0; p < 4; ++p) {
    int ol = p * 16 + r;
    float4 v;
    v.x = tile[a * 4 + 0][ol];
    v.y = tile[a * 4 + 1][ol];
    v.z = tile[a * 4 + 2][ol];
    v.w = tile[a * 4 + 3][ol];
    *reinterpret_cast<float4*>(&dst[(size_t)(o0 + ol) * GN + g0 + a * 4]) = v;
  }
}

// ---------------------------------------------------------------------------
extern "C" void kernel_launch(void* const* d_in, const int* in_sizes, int n_in,
                              void* d_out, int out_size, void* d_ws, size_t ws_size,
                              hipStream_t stream) {
  const float* x  = (const float*)d_in[0];
  const float* W  = (const float*)d_in[1];
  const float* bs = (const float*)d_in[2];
  float* out      = (float*)d_out;

  const size_t xT_elems = (size_t)BATCH * GN * CIN;
  const size_t oT_elems = (size_t)BATCH * GN * COUT;
  const bool use_ws = ws_size >= (xT_elems + oT_elems) * sizeof(ushort);

  ushort* xT   = (ushort*)d_ws;
  ushort* outT = xT + xT_elems;

  dim3 grid1(GN / 64, CIN / 64, BATCH);
  k_transpose_convert<<<grid1, 256, 0, stream>>>(x, xT);
  // DIAGNOSTIC: k2 launched twice (idempotent — identical inputs/outputs).
  // dur_new - 111.2us  ==  t(k2) + ~1us launch gap.
  k_group_gemm<<<GN / NG, 256, 0, stream>>>(xT, W, bs, out,
                                            use_ws ? outT : nullptr,
                                            use_ws ? 1 : 0);
  k_group_gemm<<<GN / NG, 256, 0, stream>>>(xT, W, bs, out,
                                            use_ws ? outT : nullptr,
                                            use_ws ? 1 : 0);
  if (use_ws) {
    dim3 grid3(GN / 64, COUT / 64, BATCH);
    k_transpose_out<<<grid3, 256, 0, stream>>>(outT, out);
  }
}

// Round 10
// 129.732 us; speedup vs baseline: 1.3076x; 1.3076x over previous
//
#include <hip/hip_runtime.h>
#include <hip/hip_bf16.h>

typedef __bf16 bf16x8 __attribute__((ext_vector_type(8)));
typedef float f32x4 __attribute__((ext_vector_type(4)));

#define GN    1024
#define BATCH 64
#define CIN   256
#define COUT  256
#define NG    4                      // g's per persistent block (k2)
#define A_ELEMS (BATCH * CIN)        // 16384 ushorts = 32 KB
#define WSLICE  8192                 // per wave, per buffer: 64 o-rows x 32 k x 4B

#define G_AS __attribute__((address_space(1)))
#define L_AS __attribute__((address_space(3)))

static __device__ __forceinline__ void gload16(const void* g, void* l) {
  __builtin_amdgcn_global_load_lds((const G_AS void*)g, (L_AS void*)l, 16, 0, 0);
}

static __device__ __forceinline__ ushort f2bf(float f) {
  __hip_bfloat16 h = __float2bfloat16(f);
  return *reinterpret_cast<ushort*>(&h);
}
static __device__ __forceinline__ float bf2f(ushort u) {
  uint v = (uint)u << 16;
  return *reinterpret_cast<float*>(&v);
}

// ---------------------------------------------------------------------------
// Kernel 1 v2: transpose+convert x[b][i][g] f32 -> xT[b][g][i^((b&7)<<3)] bf16
// Block = one b-plane x 256-g tile x full i (256). 256 blocks = 1/CU.
// Reads: 1 KB contiguous per wave-instr. Writes: full 512 B xT rows.
// LDS: bf16 tile [i=256][g pad 258] = 129 KB; pad 258 -> row=129 dwords
// (odd) so column reads spread 8 banks; writes are 2-lane/bank (free).
// ---------------------------------------------------------------------------
__global__ __launch_bounds__(256) void k_transpose_convert(
    const float* __restrict__ x, ushort* __restrict__ xT)
{
  __shared__ ushort tile[256][258];  // [i][g]
  const int g0   = blockIdx.x * 256;
  const int b    = blockIdx.y;
  const int t    = threadIdx.x;
  const int lane = t & 63;
  const int w    = t >> 6;
  const int key  = (b & 7) << 3;

  const float* xb = x + (size_t)b * CIN * GN;
#pragma unroll 4
  for (int r = 0; r < 64; ++r) {
    int i = r * 4 + w;
    float4 v = *reinterpret_cast<const float4*>(&xb[(size_t)i * GN + g0 + lane * 4]);
    ushort2 p0, p1;
    p0.x = f2bf(v.x); p0.y = f2bf(v.y);
    p1.x = f2bf(v.z); p1.y = f2bf(v.w);
    *reinterpret_cast<ushort2*>(&tile[i][lane * 4])     = p0;
    *reinterpret_cast<ushort2*>(&tile[i][lane * 4 + 2]) = p1;
  }
  __syncthreads();

  ushort* xTb = xT + (size_t)b * GN * CIN;
#pragma unroll 4
  for (int r = 0; r < 64; ++r) {
    int g = r * 4 + w;
    ushort4 u;
    u.x = tile[lane * 4 + 0][g];
    u.y = tile[lane * 4 + 1][g];
    u.z = tile[lane * 4 + 2][g];
    u.w = tile[lane * 4 + 3][g];
    int isw = (lane * 4) ^ key;  // key mult of 8 -> ushort4 stays aligned
    *reinterpret_cast<ushort4*>(&xTb[(size_t)(g0 + g) * CIN + isw]) = u;
  }
}

// ---------------------------------------------------------------------------
// Kernel 2: PERSISTENT per-group GEMM (round-6 structure, measured ~57 us,
// within ~8% of its 335 MB streaming floor). Single launch.
// ---------------------------------------------------------------------------
__global__ __launch_bounds__(256) void k_group_gemm(
    const ushort* __restrict__ xT, const float* __restrict__ W,
    const float* __restrict__ bias, float* __restrict__ out,
    ushort* __restrict__ outT, int use_ws)
{
  __shared__ __align__(16) unsigned char lds[2 * A_ELEMS * 2 + 4 * 2 * WSLICE]; // 128 KB
  ushort* lA        = (ushort*)lds;
  unsigned char* lW = lds + 2 * A_ELEMS * 2;

  const int tid  = threadIdx.x;
  const int wave = tid >> 6;
  const int lane = tid & 63;
  const int g_base = blockIdx.x * NG;

  const int arow = lane & 15;
  const int colk = (lane >> 4) * 32;
  const int kq   = (lane >> 4) << 3;
  const int oc   = 64 * wave + arow;

  unsigned char* lWw = lW + wave * (2 * WSLICE);
  const int swz_src = ((lane & 7) ^ (lane >> 3)) << 4;
  const int wrow    = lane >> 3;

  auto stage_a = [&](int gg, int ab) {
    ushort* base = lA + ab * A_ELEMS;
#pragma unroll
    for (int j = 0; j < 8; ++j) {
      int b = 16 * wave + 2 * j + (lane >> 5);
      const ushort* gsrc = xT + ((size_t)b * GN + gg) * CIN + (lane & 31) * 8;
      gload16(gsrc, base + (16 * wave + 2 * j) * CIN);
    }
  };
  auto stage_w = [&](const float* wgp, int ks, int buf) {
    unsigned char* ldb = lWw + buf * WSLICE;
    const unsigned char* gb = (const unsigned char*)wgp + (size_t)ks * 128 + swz_src;
#pragma unroll
    for (int j = 0; j < 8; ++j) {
      gload16(gb + (size_t)(8 * j + wrow) * (CIN * 4), ldb + j * 1024);
    }
  };

  // ---- prologue: bias preload (16 loads), A(g0), W0, W1 ----
  float bvv[NG][4];
#pragma unroll
  for (int gi = 0; gi < NG; ++gi)
#pragma unroll
    for (int n = 0; n < 4; ++n)
      bvv[gi][n] = bias[(g_base + gi) * COUT + oc + n * 16];
  __builtin_amdgcn_sched_barrier(0);

  stage_a(g_base, 0);
  __builtin_amdgcn_sched_barrier(0);
  {
    const float* wg0 = W + ((size_t)g_base * COUT + 64 * wave) * CIN;
    stage_w(wg0, 0, 0);
    __builtin_amdgcn_sched_barrier(0);
    stage_w(wg0, 1, 1);
    __builtin_amdgcn_sched_barrier(0);
  }
  asm volatile("s_waitcnt vmcnt(8)" ::: "memory");
  __builtin_amdgcn_sched_barrier(0);
  __builtin_amdgcn_s_barrier();

#pragma unroll
  for (int gi = 0; gi < NG; ++gi) {
    const int g = g_base + gi;
    const ushort* lAc = lA + (gi & 1) * A_ELEMS;
    const float* wgp  = W + ((size_t)g * COUT + 64 * wave) * CIN;

    f32x4 acc[4][4];
#pragma unroll
    for (int m = 0; m < 4; ++m)
#pragma unroll
      for (int n = 0; n < 4; ++n)
        acc[m][n] = {0.f, 0.f, 0.f, 0.f};

#pragma unroll
    for (int ks = 0; ks < 8; ++ks) {
      if (gi < NG - 1) {
        if (ks == 6) { asm volatile("s_waitcnt vmcnt(16)" ::: "memory"); }
        else         { asm volatile("s_waitcnt vmcnt(8)"  ::: "memory"); }
      } else {
        if (ks == 7) { asm volatile("s_waitcnt vmcnt(0)"  ::: "memory"); }
        else         { asm volatile("s_waitcnt vmcnt(8)"  ::: "memory"); }
      }
      __builtin_amdgcn_sched_barrier(0);

      unsigned char* wb = lWw + (ks & 1) * WSLICE;
      const int key = (arow & 7) << 4;

      float4 f[4][2];
#pragma unroll
      for (int n = 0; n < 4; ++n) {
        int r = n * 16 + arow;
        f[n][0] = *reinterpret_cast<const float4*>(wb + r * 128 + (colk ^ key));
        f[n][1] = *reinterpret_cast<const float4*>(wb + r * 128 + ((colk + 16) ^ key));
      }
      bf16x8 afr[4];
      const int i0 = ks * 32 + kq;
#pragma unroll
      for (int m = 0; m < 4; ++m) {
        int row = m * 16 + arow;
        afr[m] = *reinterpret_cast<const bf16x8*>(
            &lAc[row * CIN + (i0 ^ ((row & 7) << 3))]);
      }

      asm volatile("s_waitcnt lgkmcnt(0)" ::: "memory");
      __builtin_amdgcn_sched_barrier(0);
      if (ks < 6) stage_w(wgp, ks + 2, ks & 1);
      if (ks == 4 && gi < NG - 1) stage_a(g + 1, (gi & 1) ^ 1);
      __builtin_amdgcn_sched_barrier(0);

      bf16x8 bfr[4];
#pragma unroll
      for (int n = 0; n < 4; ++n) {
        bfr[n][0] = (__bf16)f[n][0].x; bfr[n][1] = (__bf16)f[n][0].y;
        bfr[n][2] = (__bf16)f[n][0].z; bfr[n][3] = (__bf16)f[n][0].w;
        bfr[n][4] = (__bf16)f[n][1].x; bfr[n][5] = (__bf16)f[n][1].y;
        bfr[n][6] = (__bf16)f[n][1].z; bfr[n][7] = (__bf16)f[n][1].w;
      }

      __builtin_amdgcn_s_setprio(1);
#pragma unroll
      for (int m = 0; m < 4; ++m)
#pragma unroll
        for (int n = 0; n < 4; ++n)
          acc[m][n] = __builtin_amdgcn_mfma_f32_16x16x32_bf16(
              afr[m], bfr[n], acc[m][n], 0, 0, 0);
      __builtin_amdgcn_s_setprio(0);
    }

    // ---- epilogue for g ----
    if (use_ws) {
#pragma unroll
      for (int m = 0; m < 4; ++m) {
#pragma unroll
        for (int n = 0; n < 4; ++n) {
          int o = oc + n * 16;
#pragma unroll
          for (int j = 0; j < 4; ++j) {
            int b = m * 16 + ((lane >> 4) << 2) + j;
            __hip_bfloat16 h = __float2bfloat16(acc[m][n][j] + bvv[gi][n]);
            outT[((size_t)b * GN + g) * COUT + o] = *reinterpret_cast<ushort*>(&h);
          }
        }
      }
    } else {
#pragma unroll
      for (int m = 0; m < 4; ++m) {
#pragma unroll
        for (int n = 0; n < 4; ++n) {
          int o = oc + n * 16;
#pragma unroll
          for (int j = 0; j < 4; ++j) {
            int b = m * 16 + ((lane >> 4) << 2) + j;
            out[((size_t)b * COUT + o) * GN + g] = acc[m][n][j] + bvv[gi][n];
          }
        }
      }
    }
    __builtin_amdgcn_sched_barrier(0);

    if (gi < NG - 1) {
      const float* wgn = W + ((size_t)(g + 1) * COUT + 64 * wave) * CIN;
      stage_w(wgn, 0, 0);
      __builtin_amdgcn_sched_barrier(0);
      stage_w(wgn, 1, 1);
      __builtin_amdgcn_sched_barrier(0);
      asm volatile("s_waitcnt vmcnt(8)" ::: "memory");
      __builtin_amdgcn_sched_barrier(0);
      __builtin_amdgcn_s_barrier();
    }
  }
}

// ---------------------------------------------------------------------------
// Kernel 3 v2: transpose outT[b][g][o] bf16 -> out[b][o][g] f32
// Block = one b-plane x 256-g tile x full o (256). 256 blocks = 1/CU.
// Reads: 1 KB contiguous (two adjacent 512 B g-rows per wave-instr).
// Writes: 1 KB contiguous float4 rows.
// ---------------------------------------------------------------------------
__global__ __launch_bounds__(256) void k_transpose_out(
    const ushort* __restrict__ outT, float* __restrict__ out)
{
  __shared__ ushort tile[256][258];  // [g][o]
  const int g0   = blockIdx.x * 256;
  const int b    = blockIdx.y;
  const int t    = threadIdx.x;
  const int lane = t & 63;
  const int w    = t >> 6;

  const ushort* src = outT + (size_t)b * GN * COUT;
#pragma unroll 4
  for (int r = 0; r < 32; ++r) {
    int g = r * 8 + w * 2 + (lane >> 5);
    int4 raw = *reinterpret_cast<const int4*>(
        &src[(size_t)(g0 + g) * COUT + (lane & 31) * 8]);
    const ushort2* ps = reinterpret_cast<const ushort2*>(&raw);
    int col = (lane & 31) * 8;
#pragma unroll
    for (int k = 0; k < 4; ++k)
      *reinterpret_cast<ushort2*>(&tile[g][col + 2 * k]) = ps[k];
  }
  __syncthreads();

  float* dst = out + (size_t)b * COUT * GN;
#pragma unroll 4
  for (int r = 0; r < 64; ++r) {
    int o = r * 4 + w;
    float4 v;
    v.x = bf2f(tile[lane * 4 + 0][o]);
    v.y = bf2f(tile[lane * 4 + 1][o]);
    v.z = bf2f(tile[lane * 4 + 2][o]);
    v.w = bf2f(tile[lane * 4 + 3][o]);
    *reinterpret_cast<float4*>(&dst[(size_t)o * GN + g0 + lane * 4]) = v;
  }
}

// ---------------------------------------------------------------------------
extern "C" void kernel_launch(void* const* d_in, const int* in_sizes, int n_in,
                              void* d_out, int out_size, void* d_ws, size_t ws_size,
                              hipStream_t stream) {
  const float* x  = (const float*)d_in[0];
  const float* W  = (const float*)d_in[1];
  const float* bs = (const float*)d_in[2];
  float* out      = (float*)d_out;

  const size_t xT_elems = (size_t)BATCH * GN * CIN;
  const size_t oT_elems = (size_t)BATCH * GN * COUT;
  const bool use_ws = ws_size >= (xT_elems + oT_elems) * sizeof(ushort);

  ushort* xT   = (ushort*)d_ws;
  ushort* outT = xT + xT_elems;

  dim3 grid1(GN / 256, BATCH);
  k_transpose_convert<<<grid1, 256, 0, stream>>>(x, xT);
  k_group_gemm<<<GN / NG, 256, 0, stream>>>(xT, W, bs, out,
                                            use_ws ? outT : nullptr,
                                            use_ws ? 1 : 0);
  if (use_ws) {
    dim3 grid3(GN / 256, BATCH);
    k_transpose_out<<<grid3, 256, 0, stream>>>(outT, out);
  }
}

// Round 11
// 111.220 us; speedup vs baseline: 1.5252x; 1.1665x over previous
//
#include <hip/hip_runtime.h>
#include <hip/hip_bf16.h>

typedef __bf16 bf16x8 __attribute__((ext_vector_type(8)));
typedef float f32x4 __attribute__((ext_vector_type(4)));
typedef unsigned short u16x8 __attribute__((ext_vector_type(8)));

#define GN    1024
#define BATCH 64
#define CIN   256
#define COUT  256
#define NG    4                      // g's per persistent block (k2)
#define A_ELEMS (BATCH * CIN)        // 16384 ushorts = 32 KB
#define WSLICE  8192                 // per wave, per buffer: 64 o-rows x 32 k x 4B

#define G_AS __attribute__((address_space(1)))
#define L_AS __attribute__((address_space(3)))

static __device__ __forceinline__ void gload16(const void* g, void* l) {
  __builtin_amdgcn_global_load_lds((const G_AS void*)g, (L_AS void*)l, 16, 0, 0);
}

static __device__ __forceinline__ ushort f2bf(float f) {
  __hip_bfloat16 h = __float2bfloat16(f);
  return *reinterpret_cast<ushort*>(&h);
}
static __device__ __forceinline__ float bf2f(ushort u) {
  uint v = (uint)u << 16;
  return *reinterpret_cast<float*>(&v);
}

// ---------------------------------------------------------------------------
// Kernel 1 v3: transpose+convert x[b][i][g] f32 -> xT[b][g][i^((b&7)<<3)] bf16
// Tile 64 g x 128 i; grid (16, 2, 64) = 2048 blocks; 33 KB LDS (~4 blocks/CU).
// Reads 256 B rows (64 g x 4B); writes 256 B rows (128 i x 2B).
// LDS f32 tile [i][g ^ keyc(i)], keyc = ((i>>5)&1)<<4 -> <=2-way banks in
// both phases (splits the {a,a+4,a+8,a+12} 4-way collision set).
// ---------------------------------------------------------------------------
__global__ __launch_bounds__(256) void k_transpose_convert(
    const float* __restrict__ x, ushort* __restrict__ xT)
{
  __shared__ float tile[128][65];  // [i][g^key]
  const int g0 = blockIdx.x * 64;
  const int i0 = blockIdx.y * 128;
  const int b  = blockIdx.z;
  const int t  = threadIdx.x;
  const int a  = t & 15;
  const int r  = t >> 4;
  const int keyb = (b & 7) << 3;

  const float* xb = x + (size_t)b * CIN * GN;
#pragma unroll
  for (int p = 0; p < 8; ++p) {
    int i = p * 16 + r;
    float4 v = *reinterpret_cast<const float4*>(
        &xb[(size_t)(i0 + i) * GN + g0 + a * 4]);
    int c = (a * 4) ^ (((i >> 5) & 1) << 4);
    tile[i][c + 0] = v.x;
    tile[i][c + 1] = v.y;
    tile[i][c + 2] = v.z;
    tile[i][c + 3] = v.w;
  }
  __syncthreads();

  ushort* xTb = xT + (size_t)b * GN * CIN;
#pragma unroll
  for (int p = 0; p < 4; ++p) {
    int g = p * 16 + r;
    u16x8 u;
#pragma unroll
    for (int k = 0; k < 8; ++k) {
      int il = a * 8 + k;
      u[k] = f2bf(tile[il][g ^ (((il >> 5) & 1) << 4)]);
    }
    int isw = (i0 + a * 8) ^ keyb;  // keyb mult of 8 -> 16B block stays intact
    *reinterpret_cast<u16x8*>(&xTb[(size_t)(g0 + g) * CIN + isw]) = u;
  }
}

// ---------------------------------------------------------------------------
// Kernel 2: PERSISTENT per-group GEMM (round-6 structure, measured ~57 us,
// within ~8% of its 335 MB streaming floor). Single launch.
// ---------------------------------------------------------------------------
__global__ __launch_bounds__(256) void k_group_gemm(
    const ushort* __restrict__ xT, const float* __restrict__ W,
    const float* __restrict__ bias, float* __restrict__ out,
    ushort* __restrict__ outT, int use_ws)
{
  __shared__ __align__(16) unsigned char lds[2 * A_ELEMS * 2 + 4 * 2 * WSLICE]; // 128 KB
  ushort* lA        = (ushort*)lds;
  unsigned char* lW = lds + 2 * A_ELEMS * 2;

  const int tid  = threadIdx.x;
  const int wave = tid >> 6;
  const int lane = tid & 63;
  const int g_base = blockIdx.x * NG;

  const int arow = lane & 15;
  const int colk = (lane >> 4) * 32;
  const int kq   = (lane >> 4) << 3;
  const int oc   = 64 * wave + arow;

  unsigned char* lWw = lW + wave * (2 * WSLICE);
  const int swz_src = ((lane & 7) ^ (lane >> 3)) << 4;
  const int wrow    = lane >> 3;

  auto stage_a = [&](int gg, int ab) {
    ushort* base = lA + ab * A_ELEMS;
#pragma unroll
    for (int j = 0; j < 8; ++j) {
      int b = 16 * wave + 2 * j + (lane >> 5);
      const ushort* gsrc = xT + ((size_t)b * GN + gg) * CIN + (lane & 31) * 8;
      gload16(gsrc, base + (16 * wave + 2 * j) * CIN);
    }
  };
  auto stage_w = [&](const float* wgp, int ks, int buf) {
    unsigned char* ldb = lWw + buf * WSLICE;
    const unsigned char* gb = (const unsigned char*)wgp + (size_t)ks * 128 + swz_src;
#pragma unroll
    for (int j = 0; j < 8; ++j) {
      gload16(gb + (size_t)(8 * j + wrow) * (CIN * 4), ldb + j * 1024);
    }
  };

  // ---- prologue: bias preload (16 loads), A(g0), W0, W1 ----
  float bvv[NG][4];
#pragma unroll
  for (int gi = 0; gi < NG; ++gi)
#pragma unroll
    for (int n = 0; n < 4; ++n)
      bvv[gi][n] = bias[(g_base + gi) * COUT + oc + n * 16];
  __builtin_amdgcn_sched_barrier(0);

  stage_a(g_base, 0);
  __builtin_amdgcn_sched_barrier(0);
  {
    const float* wg0 = W + ((size_t)g_base * COUT + 64 * wave) * CIN;
    stage_w(wg0, 0, 0);
    __builtin_amdgcn_sched_barrier(0);
    stage_w(wg0, 1, 1);
    __builtin_amdgcn_sched_barrier(0);
  }
  asm volatile("s_waitcnt vmcnt(8)" ::: "memory");
  __builtin_amdgcn_sched_barrier(0);
  __builtin_amdgcn_s_barrier();

#pragma unroll
  for (int gi = 0; gi < NG; ++gi) {
    const int g = g_base + gi;
    const ushort* lAc = lA + (gi & 1) * A_ELEMS;
    const float* wgp  = W + ((size_t)g * COUT + 64 * wave) * CIN;

    f32x4 acc[4][4];
#pragma unroll
    for (int m = 0; m < 4; ++m)
#pragma unroll
      for (int n = 0; n < 4; ++n)
        acc[m][n] = {0.f, 0.f, 0.f, 0.f};

#pragma unroll
    for (int ks = 0; ks < 8; ++ks) {
      if (gi < NG - 1) {
        if (ks == 6) { asm volatile("s_waitcnt vmcnt(16)" ::: "memory"); }
        else         { asm volatile("s_waitcnt vmcnt(8)"  ::: "memory"); }
      } else {
        if (ks == 7) { asm volatile("s_waitcnt vmcnt(0)"  ::: "memory"); }
        else         { asm volatile("s_waitcnt vmcnt(8)"  ::: "memory"); }
      }
      __builtin_amdgcn_sched_barrier(0);

      unsigned char* wb = lWw + (ks & 1) * WSLICE;
      const int key = (arow & 7) << 4;

      float4 f[4][2];
#pragma unroll
      for (int n = 0; n < 4; ++n) {
        int rr = n * 16 + arow;
        f[n][0] = *reinterpret_cast<const float4*>(wb + rr * 128 + (colk ^ key));
        f[n][1] = *reinterpret_cast<const float4*>(wb + rr * 128 + ((colk + 16) ^ key));
      }
      bf16x8 afr[4];
      const int i0 = ks * 32 + kq;
#pragma unroll
      for (int m = 0; m < 4; ++m) {
        int row = m * 16 + arow;
        afr[m] = *reinterpret_cast<const bf16x8*>(
            &lAc[row * CIN + (i0 ^ ((row & 7) << 3))]);
      }

      asm volatile("s_waitcnt lgkmcnt(0)" ::: "memory");
      __builtin_amdgcn_sched_barrier(0);
      if (ks < 6) stage_w(wgp, ks + 2, ks & 1);
      if (ks == 4 && gi < NG - 1) stage_a(g + 1, (gi & 1) ^ 1);
      __builtin_amdgcn_sched_barrier(0);

      bf16x8 bfr[4];
#pragma unroll
      for (int n = 0; n < 4; ++n) {
        bfr[n][0] = (__bf16)f[n][0].x; bfr[n][1] = (__bf16)f[n][0].y;
        bfr[n][2] = (__bf16)f[n][0].z; bfr[n][3] = (__bf16)f[n][0].w;
        bfr[n][4] = (__bf16)f[n][1].x; bfr[n][5] = (__bf16)f[n][1].y;
        bfr[n][6] = (__bf16)f[n][1].z; bfr[n][7] = (__bf16)f[n][1].w;
      }

      __builtin_amdgcn_s_setprio(1);
#pragma unroll
      for (int m = 0; m < 4; ++m)
#pragma unroll
        for (int n = 0; n < 4; ++n)
          acc[m][n] = __builtin_amdgcn_mfma_f32_16x16x32_bf16(
              afr[m], bfr[n], acc[m][n], 0, 0, 0);
      __builtin_amdgcn_s_setprio(0);
    }

    // ---- epilogue for g ----
    if (use_ws) {
#pragma unroll
      for (int m = 0; m < 4; ++m) {
#pragma unroll
        for (int n = 0; n < 4; ++n) {
          int o = oc + n * 16;
#pragma unroll
          for (int j = 0; j < 4; ++j) {
            int b = m * 16 + ((lane >> 4) << 2) + j;
            __hip_bfloat16 h = __float2bfloat16(acc[m][n][j] + bvv[gi][n]);
            outT[((size_t)b * GN + g) * COUT + o] = *reinterpret_cast<ushort*>(&h);
          }
        }
      }
    } else {
#pragma unroll
      for (int m = 0; m < 4; ++m) {
#pragma unroll
        for (int n = 0; n < 4; ++n) {
          int o = oc + n * 16;
#pragma unroll
          for (int j = 0; j < 4; ++j) {
            int b = m * 16 + ((lane >> 4) << 2) + j;
            out[((size_t)b * COUT + o) * GN + g] = acc[m][n][j] + bvv[gi][n];
          }
        }
      }
    }
    __builtin_amdgcn_sched_barrier(0);

    if (gi < NG - 1) {
      const float* wgn = W + ((size_t)(g + 1) * COUT + 64 * wave) * CIN;
      stage_w(wgn, 0, 0);
      __builtin_amdgcn_sched_barrier(0);
      stage_w(wgn, 1, 1);
      __builtin_amdgcn_sched_barrier(0);
      asm volatile("s_waitcnt vmcnt(8)" ::: "memory");
      __builtin_amdgcn_sched_barrier(0);
      __builtin_amdgcn_s_barrier();
    }
  }
}

// ---------------------------------------------------------------------------
// Kernel 3 v3: transpose outT[b][g][o] bf16 -> out[b][o][g] f32
// Tile 64 g x 128 o; grid (16, 2, 64) = 2048 blocks; 33 KB LDS.
// Reads 256 B rows (128 o x 2B); writes 256 B rows (64 g x 4B).
// LDS f32 tile [o][g ^ keyc(o)], keyc = ((o>>5)&1)<<4 -> <=2-way banks.
// ---------------------------------------------------------------------------
__global__ __launch_bounds__(256) void k_transpose_out(
    const ushort* __restrict__ outT, float* __restrict__ out)
{
  __shared__ float tile[128][65];  // [o][g^key]
  const int g0 = blockIdx.x * 64;
  const int o0 = blockIdx.y * 128;
  const int b  = blockIdx.z;
  const int t  = threadIdx.x;
  const int a  = t & 15;
  const int r  = t >> 4;

  const ushort* src = outT + (size_t)b * GN * COUT;
#pragma unroll
  for (int p = 0; p < 4; ++p) {
    int g = p * 16 + r;
    u16x8 u = *reinterpret_cast<const u16x8*>(
        &src[(size_t)(g0 + g) * COUT + o0 + a * 8]);
#pragma unroll
    for (int k = 0; k < 8; ++k) {
      int ol = a * 8 + k;
      tile[ol][g ^ (((ol >> 5) & 1) << 4)] = bf2f(u[k]);
    }
  }
  __syncthreads();

  float* dst = out + (size_t)b * COUT * GN;
#pragma unroll
  for (int p = 0; p < 8; ++p) {
    int o = p * 16 + r;
    int c = (a * 4) ^ (((o >> 5) & 1) << 4);
    float4 v;
    v.x = tile[o][c + 0];
    v.y = tile[o][c + 1];
    v.z = tile[o][c + 2];
    v.w = tile[o][c + 3];
    *reinterpret_cast<float4*>(
        &dst[(size_t)(o0 + o) * GN + g0 + a * 4]) = v;
  }
}

// ---------------------------------------------------------------------------
extern "C" void kernel_launch(void* const* d_in, const int* in_sizes, int n_in,
                              void* d_out, int out_size, void* d_ws, size_t ws_size,
                              hipStream_t stream) {
  const float* x  = (const float*)d_in[0];
  const float* W  = (const float*)d_in[1];
  const float* bs = (const float*)d_in[2];
  float* out      = (float*)d_out;

  const size_t xT_elems = (size_t)BATCH * GN * CIN;
  const size_t oT_elems = (size_t)BATCH * GN * COUT;
  const bool use_ws = ws_size >= (xT_elems + oT_elems) * sizeof(ushort);

  ushort* xT   = (ushort*)d_ws;
  ushort* outT = xT + xT_elems;

  dim3 grid1(GN / 64, CIN / 128, BATCH);
  k_transpose_convert<<<grid1, 256, 0, stream>>>(x, xT);
  k_group_gemm<<<GN / NG, 256, 0, stream>>>(xT, W, bs, out,
                                            use_ws ? outT : nullptr,
                                            use_ws ? 1 : 0);
  if (use_ws) {
    dim3 grid3(GN / 64, COUT / 128, BATCH);
    k_transpose_out<<<grid3, 256, 0, stream>>>(outT, out);
  }
}